// Round 4
// baseline (351.067 us; speedup 1.0000x reference)
//
#include <hip/hip_runtime.h>
#include <hip/hip_bf16.h>
#include <stdint.h>

#define BB   8
#define CCH  128
#define HH   256
#define WWD  256
#define OCC  64
#define HWW  (HH*WWD)
#define PLANE (BB*HWW*32)          // elems per 32-ch plane of xn2
#define PITCH 208                  // padded LDS px pitch (bytes); 192 payload + 16 pad

typedef __attribute__((ext_vector_type(8))) short  bf16x8;
typedef __attribute__((ext_vector_type(4))) float  f32x4;
typedef __attribute__((ext_vector_type(4))) unsigned int u32x4;
typedef __attribute__((ext_vector_type(2))) float  f32x2;

static __device__ __forceinline__ unsigned cvt_pk_bf16(float lo, float hi) {
    unsigned r;
    asm("v_cvt_pk_bf16_f32 %0, %1, %2" : "=v"(r) : "v"(lo), "v"(hi));
    return r;
}
static __device__ __forceinline__ float bf16lo_to_f(unsigned u) {
    union { unsigned u; float f; } c; c.u = u << 16; return c.f;
}
static __device__ __forceinline__ float bf16hi_to_f(unsigned u) {
    union { unsigned u; float f; } c; c.u = u & 0xffff0000u; return c.f;
}

// Repack Wc (OC, Q*C, 3, 3) fp32 -> Wb2: per-fragment lane-order bf16.
// frag = ((tap*3+q)*4+cc)*4+nt ; within frag: lane*8 contiguous bf16,
// lane -> (oc = nt*16 + (lane&15), k = cc*32 + (lane>>4)*8 + j).
__global__ void prep_w(const float* __restrict__ Wc, unsigned short* __restrict__ Wb2) {
    int task = blockIdx.x * 256 + threadIdx.x;    // 27648 tasks, one bf16x8 each
    int lane = task & 63;
    int frag = task >> 6;
    int nt   = frag & 3;
    int cc   = (frag >> 2) & 3;
    int tq   = frag >> 4;                         // tap*3+q, 0..26
    int q    = tq % 3;
    int tap  = tq / 3;
    int oc   = nt * 16 + (lane & 15);
    int kb   = cc * 32 + (lane >> 4) * 8;
    u32x4 o;
    #pragma unroll
    for (int k = 0; k < 4; ++k) {
        float v0 = Wc[(size_t)(oc * 384 + q * 128 + kb + 2 * k) * 9 + tap];
        float v1 = Wc[(size_t)(oc * 384 + q * 128 + kb + 2 * k + 1) * 9 + tap];
        o[k] = cvt_pk_bf16(v0, v1);
    }
    *(u32x4*)(Wb2 + (size_t)task * 8) = o;
}

// Per-pixel LayerNorm over C=128; write xn2 as 4 planes [cc][b][y][x][32ch] bf16
__global__ __launch_bounds__(256) void ln_kernel(
        const float* __restrict__ x, const float* __restrict__ gamma,
        const float* __restrict__ beta, unsigned short* __restrict__ xn2) {
    int p  = blockIdx.x * 256 + threadIdx.x;      // global pixel
    int b  = p >> 16;
    int hw = p & 65535;
    const float* xb = x + (size_t)b * CCH * HWW + hw;
    unsigned buf[64];
    float sum = 0.f, sumsq = 0.f;
    #pragma unroll
    for (int cp = 0; cp < 64; ++cp) {
        float v0 = xb[(size_t)(2 * cp) * HWW];
        float v1 = xb[(size_t)(2 * cp + 1) * HWW];
        sum   += v0 + v1;
        sumsq += v0 * v0 + v1 * v1;
        buf[cp] = cvt_pk_bf16(v0, v1);
    }
    float mu  = sum * (1.f / 128.f);
    float var = sumsq * (1.f / 128.f) - mu * mu;
    float rs  = rsqrtf(var + 1e-5f);
    size_t pix = (size_t)p * 32;
    #pragma unroll
    for (int g = 0; g < 16; ++g) {
        u32x4 o;
        #pragma unroll
        for (int k = 0; k < 4; ++k) {
            int cp = g * 4 + k;
            float f0 = bf16lo_to_f(buf[cp]);
            float f1 = bf16hi_to_f(buf[cp]);
            int c0 = cp * 2, c1 = cp * 2 + 1;
            float y0 = fmaf((f0 - mu) * rs, gamma[c0], beta[c0]);
            float y1 = fmaf((f1 - mu) * rs, gamma[c1], beta[c1]);
            o[k] = cvt_pk_bf16(y0, y1);
        }
        *(u32x4*)(xn2 + (size_t)(g >> 2) * PLANE + pix + (g & 3) * 8) = o;
    }
}

// Implicit-GEMM conv. Block = 8 rows x 32 px x 64 oc; 8 waves (each 1 row x 32 px).
// 512 thr, 2 blocks/CU -> 4 waves/SIMD for latency hiding. Pipelined staging (T14)
// + tap-level A/B register double-buffer + setprio.
__global__ __launch_bounds__(512, 4) void conv_kernel(
        const unsigned short* __restrict__ xn2,
        const unsigned short* __restrict__ Wb2,
        float* __restrict__ out) {
    // LDS: P[row 10][px 34][PITCH bytes: q*64 + granule*16, 16B pad] = 70720 B
    __shared__ __align__(16) unsigned char P[10 * 34 * PITCH];

    int bid = blockIdx.x;
    int bx  = bid & 7;          // x tile
    int by  = (bid >> 3) & 31;  // y tile
    int b   = bid >> 8;
    int x0  = bx * 32;
    int y0  = by * 8;
    int tid  = threadIdx.x;
    int lane = tid & 63;
    int w    = tid >> 6;        // 0..7, wave owns row y0+w
    int l15  = lane & 15;
    int l4   = lane >> 4;

    f32x4 acc[2][4];
    #pragma unroll
    for (int mt = 0; mt < 2; ++mt)
        #pragma unroll
        for (int nt = 0; nt < 4; ++nt)
            acc[mt][nt] = (f32x4){0.f, 0.f, 0.f, 0.f};

    // ---- staging geometry (cc-invariant): 1360 items over 512 threads ----
    int offg[3];                 // elem offset within a plane (per batch)
    int woff[3];                 // LDS byte offset
    bool vldf[3], wrf[3];
    #pragma unroll
    for (int it = 0; it < 3; ++it) {
        int item = tid + it * 512;
        bool ok  = item < 1360;
        int ii   = ok ? item : 0;
        int row  = ii / 136;
        int rem  = ii - row * 136;
        int px   = rem >> 2;
        int g    = rem & 3;
        int yy   = y0 - 1 + row;
        int xx   = x0 - 1 + px;
        bool inb = ok && (unsigned)yy < 256u && (unsigned)xx < 256u;
        offg[it] = (yy * 256 + xx) * 32 + g * 8;
        woff[it] = (row * 34 + px) * PITCH + g * 16;
        vldf[it] = inb;
        wrf[it]  = ok;
    }

    const unsigned short* xpb = xn2 + (size_t)b * HWW * 32;
    const bf16x8* wlane = (const bf16x8*)Wb2 + lane;
    const unsigned char* pa = P + (w * 34 + l15) * PITCH + l4 * 16;

    // ---- prologue: issue chunk-0 staging loads ----
    u32x4 rs[3];
    #pragma unroll
    for (int it = 0; it < 3; ++it) {
        u32x4 v = (u32x4){0u, 0u, 0u, 0u};
        if (vldf[it]) v = *(const u32x4*)(xpb + offg[it]);
        rs[it] = v;
    }

    #pragma unroll 1
    for (int cc = 0; cc < 4; ++cc) {
        if (cc > 0) __syncthreads();          // all waves done reading prev chunk
        // ---- write powers to LDS from staged regs ----
        #pragma unroll
        for (int it = 0; it < 3; ++it) {
            if (!wrf[it]) continue;
            u32x4 u1 = rs[it];
            u32x4 u2, u3;
            #pragma unroll
            for (int k = 0; k < 4; ++k) {
                float f0 = bf16lo_to_f(u1[k]);
                float f1 = bf16hi_to_f(u1[k]);
                float s0 = f0 * f0, s1 = f1 * f1;
                u2[k] = cvt_pk_bf16(s0, s1);
                u3[k] = cvt_pk_bf16(s0 * f0, s1 * f1);
            }
            unsigned char* cell = P + woff[it];
            *(u32x4*)(cell)       = u1;
            *(u32x4*)(cell + 64)  = u2;
            *(u32x4*)(cell + 128) = u3;
        }
        __syncthreads();

        // ---- issue chunk cc+1 staging loads (fly under the MFMAs below) ----
        if (cc < 3) {
            const unsigned short* xpn = xpb + (size_t)(cc + 1) * PLANE;
            #pragma unroll
            for (int it = 0; it < 3; ++it) {
                u32x4 v = (u32x4){0u, 0u, 0u, 0u};
                if (vldf[it]) v = *(const u32x4*)(xpn + offg[it]);
                rs[it] = v;
            }
        }

        // ---- 27 taps, software-pipelined A/B fragment prefetch ----
        const bf16x8* wcc = wlane + cc * 4 * 64;
        bf16x8 av[2][2], bvv[2][4];
        #pragma unroll
        for (int mt = 0; mt < 2; ++mt)
            av[0][mt] = *(const bf16x8*)(pa + (mt * 16) * PITCH);
        #pragma unroll
        for (int nt = 0; nt < 4; ++nt)
            bvv[0][nt] = wcc[nt * 64];

        #pragma unroll
        for (int tq = 0; tq < 27; ++tq) {
            int cur = tq & 1, nxt = cur ^ 1;
            if (tq < 26) {
                int t2 = tq + 1;
                int ky = t2 / 9, kx = (t2 / 3) % 3, q = t2 % 3;
                #pragma unroll
                for (int mt = 0; mt < 2; ++mt)
                    av[nxt][mt] = *(const bf16x8*)(pa
                        + ky * (34 * PITCH)
                        + (mt * 16 + kx) * PITCH + q * 64);
                #pragma unroll
                for (int nt = 0; nt < 4; ++nt)
                    bvv[nxt][nt] = wcc[(t2 * 16 + nt) * 64];
            }
            __builtin_amdgcn_s_setprio(1);
            #pragma unroll
            for (int nt = 0; nt < 4; ++nt)
                #pragma unroll
                for (int mt = 0; mt < 2; ++mt)
                    acc[mt][nt] = __builtin_amdgcn_mfma_f32_16x16x32_bf16(
                        av[cur][mt], bvv[cur][nt], acc[mt][nt], 0, 0, 0);
            __builtin_amdgcn_s_setprio(0);
        }
    }

    // ---- epilogue: fused PixelUnshuffle(2) ----
    int y  = y0 + w;
    int s  = w & 1;
    int y2 = y >> 1;
    #pragma unroll
    for (int mt = 0; mt < 2; ++mt) {
        int X0 = x0 + mt * 16 + l4 * 4;   // even
        int x2 = X0 >> 1;
        #pragma unroll
        for (int nt = 0; nt < 4; ++nt) {
            int oc = nt * 16 + l15;
            #pragma unroll
            for (int rr = 0; rr < 2; ++rr) {
                int ch = oc * 4 + s * 2 + rr;
                size_t off = ((size_t)(b * 256 + ch) * 128 + y2) * 128 + x2;
                f32x2 v;
                v.x = acc[mt][nt][rr];
                v.y = acc[mt][nt][rr + 2];
                *(f32x2*)(out + off) = v;
            }
        }
    }
}

extern "C" void kernel_launch(void* const* d_in, const int* in_sizes, int n_in,
                              void* d_out, int out_size, void* d_ws, size_t ws_size,
                              hipStream_t stream) {
    const float* x     = (const float*)d_in[0];
    const float* gamma = (const float*)d_in[1];
    const float* beta  = (const float*)d_in[2];
    const float* Wc    = (const float*)d_in[3];
    float* out = (float*)d_out;

    const size_t xn_bytes = (size_t)4 * PLANE * 2;               // 134217728
    const size_t wb_bytes = (size_t)27 * 16 * 512 * 2;           // 442368
    if (ws_size < xn_bytes + wb_bytes) return;                   // visible failure
    unsigned short* xn2 = (unsigned short*)d_ws;
    unsigned short* Wb2 = (unsigned short*)((char*)d_ws + xn_bytes);

    hipLaunchKernelGGL(prep_w, dim3(108), dim3(256), 0, stream, Wc, Wb2);
    hipLaunchKernelGGL(ln_kernel, dim3(2048), dim3(256), 0, stream, x, gamma, beta, xn2);
    hipLaunchKernelGGL(conv_kernel, dim3(2048), dim3(512), 0, stream, xn2, Wb2, out);
}

// Round 5
// 326.122 us; speedup vs baseline: 1.0765x; 1.0765x over previous
//
#include <hip/hip_runtime.h>
#include <hip/hip_bf16.h>
#include <stdint.h>

#define BB   8
#define CCH  128
#define HH   256
#define WWD  256
#define OCC  64
#define HWW  (HH*WWD)
#define PLANE (BB*HWW*32)          // elems per 32-ch plane of xn2

typedef __attribute__((ext_vector_type(8)))  short  bf16x8;
typedef __attribute__((ext_vector_type(16))) float  f32x16;
typedef __attribute__((ext_vector_type(4)))  unsigned int u32x4;
typedef __attribute__((ext_vector_type(2)))  float  f32x2;

static __device__ __forceinline__ unsigned cvt_pk_bf16(float lo, float hi) {
    unsigned r;
    asm("v_cvt_pk_bf16_f32 %0, %1, %2" : "=v"(r) : "v"(lo), "v"(hi));
    return r;
}
static __device__ __forceinline__ float bf16lo_to_f(unsigned u) {
    union { unsigned u; float f; } c; c.u = u << 16; return c.f;
}
static __device__ __forceinline__ float bf16hi_to_f(unsigned u) {
    union { unsigned u; float f; } c; c.u = u & 0xffff0000u; return c.f;
}

// Repack Wc (OC, Q*C, 3, 3) fp32 -> Wb3 in 32x32x16-fragment lane order.
// frag f = ((tq*4 + cc)*4) + kh*2 + nt, tq = tap*3 + q.
// lane -> oc = nt*32 + (lane&31), k = cc*32 + kh*16 + (lane>>5)*8 + j (j=0..7).
__global__ void prep_w(const float* __restrict__ Wc, unsigned short* __restrict__ Wb3) {
    int t = blockIdx.x * 256 + threadIdx.x;       // 27648 tasks, one bf16x8 each
    int lane = t & 63;
    int f    = t >> 6;                            // 0..431
    int nt   = f & 1;
    int kh   = (f >> 1) & 1;
    int cc   = (f >> 2) & 3;
    int tq   = f >> 4;                            // 0..26
    int q    = tq % 3;
    int tap  = tq / 3;
    int oc   = nt * 32 + (lane & 31);
    int kb   = cc * 32 + kh * 16 + (lane >> 5) * 8;
    u32x4 o;
    #pragma unroll
    for (int k = 0; k < 4; ++k) {
        float v0 = Wc[(size_t)(oc * 384 + q * 128 + kb + 2 * k) * 9 + tap];
        float v1 = Wc[(size_t)(oc * 384 + q * 128 + kb + 2 * k + 1) * 9 + tap];
        o[k] = cvt_pk_bf16(v0, v1);
    }
    *(u32x4*)(Wb3 + (size_t)t * 8) = o;
}

// Per-pixel LayerNorm over C=128; write xn2 as 4 planes [cc][b][y][x][32ch] bf16
__global__ __launch_bounds__(256) void ln_kernel(
        const float* __restrict__ x, const float* __restrict__ gamma,
        const float* __restrict__ beta, unsigned short* __restrict__ xn2) {
    int p  = blockIdx.x * 256 + threadIdx.x;      // global pixel
    int b  = p >> 16;
    int hw = p & 65535;
    const float* xb = x + (size_t)b * CCH * HWW + hw;
    unsigned buf[64];
    float sum = 0.f, sumsq = 0.f;
    #pragma unroll
    for (int cp = 0; cp < 64; ++cp) {
        float v0 = xb[(size_t)(2 * cp) * HWW];
        float v1 = xb[(size_t)(2 * cp + 1) * HWW];
        sum   += v0 + v1;
        sumsq += v0 * v0 + v1 * v1;
        buf[cp] = cvt_pk_bf16(v0, v1);
    }
    float mu  = sum * (1.f / 128.f);
    float var = sumsq * (1.f / 128.f) - mu * mu;
    float rs  = rsqrtf(var + 1e-5f);
    size_t pix = (size_t)p * 32;
    #pragma unroll
    for (int g = 0; g < 16; ++g) {
        u32x4 o;
        #pragma unroll
        for (int k = 0; k < 4; ++k) {
            int cp = g * 4 + k;
            float f0 = bf16lo_to_f(buf[cp]);
            float f1 = bf16hi_to_f(buf[cp]);
            int c0 = cp * 2, c1 = cp * 2 + 1;
            float y0 = fmaf((f0 - mu) * rs, gamma[c0], beta[c0]);
            float y1 = fmaf((f1 - mu) * rs, gamma[c1], beta[c1]);
            o[k] = cvt_pk_bf16(y0, y1);
        }
        *(u32x4*)(xn2 + (size_t)(g >> 2) * PLANE + pix + (g & 3) * 8) = o;
    }
}

// Implicit-GEMM conv, 32x32x16 MFMA. Block = 8 rows x 32 px x 64 oc; 4 waves,
// wave = 2 row-tiles (M=32 px each) x 2 oc-tiles (N=32). K = 4 cc-chunks x 32ch.
// LDS P[row 10][slot 12 = q*4 + g2][px 34][16B]: A ds_read_b128 is contiguous
// 512B per 32-lane group -> conflict-free. T14 staging split + tap-level
// A/B register double-buffer + setprio.
__global__ __launch_bounds__(256, 2) void conv_kernel(
        const unsigned short* __restrict__ xn2,
        const unsigned short* __restrict__ Wb3,
        float* __restrict__ out) {
    __shared__ __align__(16) unsigned char P[10 * 12 * 34 * 16];   // 65280 B

    int bid = blockIdx.x;
    int bx  = bid & 7;          // x tile
    int by  = (bid >> 3) & 31;  // y tile
    int b   = bid >> 8;
    int x0  = bx * 32;
    int y0  = by * 8;
    int tid  = threadIdx.x;
    int lane = tid & 63;
    int w    = tid >> 6;        // wave owns rows {2w, 2w+1}
    int l31  = lane & 31;
    int kb   = lane >> 5;       // k-granule bit

    f32x16 acc[2][2];
    #pragma unroll
    for (int mt = 0; mt < 2; ++mt)
        #pragma unroll
        for (int nt = 0; nt < 2; ++nt)
            #pragma unroll
            for (int r = 0; r < 16; ++r)
                acc[mt][nt][r] = 0.f;

    // ---- staging geometry (cc-invariant): it = row*136 + px*4 + g2 ----
    int offg[6];                 // elem offset within a plane
    int woff[6];                 // LDS offset in 16B units (q=0 slot)
    bool vldf[6], wrf[6];
    #pragma unroll
    for (int it = 0; it < 6; ++it) {
        int item = tid + it * 256;
        bool ok  = item < 1360;
        int ii   = ok ? item : 0;
        int row  = ii / 136;
        int rem  = ii - row * 136;
        int px   = rem >> 2;
        int g2   = rem & 3;
        int yy   = y0 - 1 + row;
        int xx   = x0 - 1 + px;
        bool inb = ok && (unsigned)yy < 256u && (unsigned)xx < 256u;
        offg[it] = (yy * 256 + xx) * 32 + g2 * 8;
        woff[it] = (row * 12 + g2) * 34 + px;
        vldf[it] = inb;
        wrf[it]  = ok;
    }

    const unsigned short* xpb = xn2 + (size_t)b * HWW * 32;
    const bf16x8* wlane = (const bf16x8*)Wb3 + lane;
    const unsigned char* pa = P + ((size_t)kb * 34 + l31) * 16;  // lane part of A addr

    // ---- prologue: issue chunk-0 staging loads ----
    u32x4 rs[6];
    #pragma unroll
    for (int it = 0; it < 6; ++it) {
        u32x4 v = (u32x4){0u, 0u, 0u, 0u};
        if (vldf[it]) v = *(const u32x4*)(xpb + offg[it]);
        rs[it] = v;
    }

    #pragma unroll 1
    for (int cc = 0; cc < 4; ++cc) {
        if (cc > 0) __syncthreads();          // all waves done reading prev chunk
        // ---- write powers to LDS from staged regs ----
        #pragma unroll
        for (int it = 0; it < 6; ++it) {
            if (!wrf[it]) continue;
            u32x4 u1 = rs[it];
            u32x4 u2, u3;
            #pragma unroll
            for (int k = 0; k < 4; ++k) {
                float f0 = bf16lo_to_f(u1[k]);
                float f1 = bf16hi_to_f(u1[k]);
                float s0 = f0 * f0, s1 = f1 * f1;
                u2[k] = cvt_pk_bf16(s0, s1);
                u3[k] = cvt_pk_bf16(s0 * f0, s1 * f1);
            }
            unsigned char* cell = P + (size_t)woff[it] * 16;
            *(u32x4*)(cell)            = u1;   // q=0
            *(u32x4*)(cell + 4*34*16)  = u2;   // q=1
            *(u32x4*)(cell + 8*34*16)  = u3;   // q=2
        }
        __syncthreads();

        // ---- issue chunk cc+1 staging loads (fly under the MFMAs below) ----
        if (cc < 3) {
            const unsigned short* xpn = xpb + (size_t)(cc + 1) * PLANE;
            #pragma unroll
            for (int it = 0; it < 6; ++it) {
                u32x4 v = (u32x4){0u, 0u, 0u, 0u};
                if (vldf[it]) v = *(const u32x4*)(xpn + offg[it]);
                rs[it] = v;
            }
        }

        // ---- 27 taps, software-pipelined A/B fragment prefetch ----
        const bf16x8* wcc = wlane + (size_t)cc * 4 * 64;
        bf16x8 av[2][2][2], bv[2][2][2];      // [buf][mt or nt][kh]
        #pragma unroll
        for (int mt = 0; mt < 2; ++mt)
            #pragma unroll
            for (int kh = 0; kh < 2; ++kh)
                av[0][mt][kh] = *(const bf16x8*)(pa
                    + (size_t)(((2 * w + mt) * 12 + kh * 2) * 34) * 16);
        #pragma unroll
        for (int nt = 0; nt < 2; ++nt)
            #pragma unroll
            for (int kh = 0; kh < 2; ++kh)
                bv[0][nt][kh] = wcc[(kh * 2 + nt) * 64];

        #pragma unroll
        for (int tq = 0; tq < 27; ++tq) {
            const int cur = tq & 1, nxt = cur ^ 1;
            if (tq < 26) {
                const int t2 = tq + 1;
                const int ky = t2 / 9, kx = (t2 / 3) % 3, q = t2 % 3;
                #pragma unroll
                for (int mt = 0; mt < 2; ++mt)
                    #pragma unroll
                    for (int kh = 0; kh < 2; ++kh)
                        av[nxt][mt][kh] = *(const bf16x8*)(pa
                            + (size_t)((((2 * w + mt + ky) * 12 + q * 4 + kh * 2) * 34)
                                       + kx) * 16);
                #pragma unroll
                for (int nt = 0; nt < 2; ++nt)
                    #pragma unroll
                    for (int kh = 0; kh < 2; ++kh)
                        bv[nxt][nt][kh] = wcc[((size_t)t2 * 16 + kh * 2 + nt) * 64];
            }
            __builtin_amdgcn_s_setprio(1);
            #pragma unroll
            for (int kh = 0; kh < 2; ++kh)
                #pragma unroll
                for (int nt = 0; nt < 2; ++nt)
                    #pragma unroll
                    for (int mt = 0; mt < 2; ++mt)
                        acc[mt][nt] = __builtin_amdgcn_mfma_f32_32x32x16_bf16(
                            av[cur][mt][kh], bv[cur][nt][kh], acc[mt][nt], 0, 0, 0);
            __builtin_amdgcn_s_setprio(0);
        }
    }

    // ---- epilogue: fused PixelUnshuffle(2) ----
    // C/D 32x32: col(oc) = lane&31, row(px) = (reg&3) + 8*(reg>>2) + 4*(lane>>5)
    #pragma unroll
    for (int mt = 0; mt < 2; ++mt) {
        int y  = y0 + 2 * w + mt;
        int s  = mt;                 // y&1 (y0, 2w even)
        int y2 = y >> 1;
        #pragma unroll
        for (int nt = 0; nt < 2; ++nt) {
            int oc = nt * 32 + l31;
            #pragma unroll
            for (int p = 0; p < 8; ++p) {
                const int r  = (p & 1) + (p >> 1) * 4;       // 0,1,4,5,8,9,12,13
                int px = (r & 3) + 8 * (r >> 2) + 4 * kb;
                int x  = x0 + px;
                int ch = oc * 4 + s * 2 + (x & 1);
                int x2 = x >> 1;
                size_t off = ((size_t)(b * 256 + ch) * 128 + y2) * 128 + x2;
                f32x2 v;
                v.x = acc[mt][nt][r];
                v.y = acc[mt][nt][r + 2];
                *(f32x2*)(out + off) = v;
            }
        }
    }
}

extern "C" void kernel_launch(void* const* d_in, const int* in_sizes, int n_in,
                              void* d_out, int out_size, void* d_ws, size_t ws_size,
                              hipStream_t stream) {
    const float* x     = (const float*)d_in[0];
    const float* gamma = (const float*)d_in[1];
    const float* beta  = (const float*)d_in[2];
    const float* Wc    = (const float*)d_in[3];
    float* out = (float*)d_out;

    const size_t xn_bytes = (size_t)4 * PLANE * 2;               // 134217728
    const size_t wb_bytes = (size_t)27648 * 16;                  // 442368
    if (ws_size < xn_bytes + wb_bytes) return;                   // visible failure
    unsigned short* xn2 = (unsigned short*)d_ws;
    unsigned short* Wb3 = (unsigned short*)((char*)d_ws + xn_bytes);

    hipLaunchKernelGGL(prep_w, dim3(108), dim3(256), 0, stream, Wc, Wb3);
    hipLaunchKernelGGL(ln_kernel, dim3(2048), dim3(256), 0, stream, x, gamma, beta, xn2);
    hipLaunchKernelGGL(conv_kernel, dim3(2048), dim3(256), 0, stream, xn2, Wb3, out);
}